// Round 15
// baseline (213.238 us; speedup 1.0000x reference)
//
#include <hip/hip_runtime.h>
#include <hip/hip_bf16.h>
#include <hip/hip_fp16.h>

// MSA: B=2, S=4096, D=256, H=4, DH=64. fp32 in/out, bf16 MFMA internally.
// R15: fuse combine into attn (split-K last-block reduction): per-instance
//      atomic counter; last-finishing wave acquires + combines 4 splits +
//      writes final output. Removes the combine launch (~5us) and overlaps
//      reduction with remaining attn blocks. __threadfence() both sides
//      (device scope, cross-XCD visibility per G16). Deterministic: fixed
//      sp-order per-lane sums. Attn loop body unchanged (R13/R14, 44us,
//      sum-of-pipes floor; regs <=124 hard rule).

#define B_   2
#define S_   4096
#define D_   256
#define H_   4
#define DH_  64
#define BH_  8
#define NTOK (BH_*S_*DH_)   // elements per Q/K/V buffer

#define KVB  64             // kv tile per step
#define QW   32             // q rows per wave
#define NW   8              // waves per block
#define QB   (QW*NW)        // 256 q rows per block
#define NINST (BH_*(S_/QW)) // 1024 q-wave instances

typedef short v8s __attribute__((ext_vector_type(8)));
typedef float v16f __attribute__((ext_vector_type(16)));
typedef float v4f __attribute__((ext_vector_type(4)));
typedef unsigned v4u __attribute__((ext_vector_type(4)));
typedef unsigned v2u __attribute__((ext_vector_type(2)));
typedef int v2i __attribute__((ext_vector_type(2)));

#define QSCL (0.125f * 1.4426950408889634f)   // 1/sqrt(64) * log2(e)

static __device__ __forceinline__ short f2bf(float f) {
    __hip_bfloat16 h = __float2bfloat16(f);
    return *reinterpret_cast<short*>(&h);
}
static __device__ __forceinline__ unsigned cvtpk(float lo, float hi) {
    unsigned r;
    asm("v_cvt_pk_bf16_f32 %0, %1, %2" : "=v"(r) : "v"(lo), "v"(hi));
    return r;
}
// Raw v_exp_f32: args bounded (|s|<~3 in exp2 domain), no wrapper needed.
static __device__ __forceinline__ float fexp2(float x) {
#if __has_builtin(__builtin_amdgcn_exp2f)
    return __builtin_amdgcn_exp2f(x);
#else
    float r;
    asm("v_exp_f32 %0, %1" : "=v"(r) : "v"(x));
    return r;
#endif
}
static __device__ __forceinline__ void pl32swap(unsigned &a, unsigned &b) {
#if __has_builtin(__builtin_amdgcn_permlane32_swap)
    v2i r = __builtin_amdgcn_permlane32_swap((int)a, (int)b, false, false);
    a = (unsigned)r[0]; b = (unsigned)r[1];
#else
    asm volatile("v_permlane32_swap_b32 %0, %1" : "+v"(a), "+v"(b));
#endif
}
// cross-half (lane i <-> i+32) add via permlane self-swap
static __device__ __forceinline__ float xadd32(float x) {
    unsigned a = __builtin_bit_cast(unsigned, x), b = a;
    pl32swap(a, b);
    return __builtin_bit_cast(float, a) + __builtin_bit_cast(float, b);
}
static __device__ __forceinline__ v16f vz16() {
    v16f z;
    #pragma unroll
    for (int i = 0; i < 16; ++i) z[i] = 0.f;
    return z;
}
static __device__ __forceinline__ v8s cvt8(const float* p) {
    v4f f0 = *(const v4f*)(p);
    v4f f1 = *(const v4f*)(p + 4);
    v4u u = { cvtpk(f0[0], f0[1]), cvtpk(f0[2], f0[3]),
              cvtpk(f1[0], f1[1]), cvtpk(f1[2], f1[3]) };
    return __builtin_bit_cast(v8s, u);
}

// ---------------------------------------------------------------------------
// Kernel 1: MFMA QKV projection (R5, unchanged).
//   Q: [BH][S][DH] pre-scaled by QSCL; K: [BH][S][DH]; Vt: [BH][DH][S].
// ---------------------------------------------------------------------------
__global__ __launch_bounds__(128) void qkv_proj_mfma(
    const float* __restrict__ x,
    const float* __restrict__ qw, const float* __restrict__ qb,
    const float* __restrict__ kw, const float* __restrict__ kb,
    const float* __restrict__ vw, const float* __restrict__ vb,
    short* __restrict__ Qo, short* __restrict__ Ko, short* __restrict__ Vt)
{
    const int t   = threadIdx.x;
    const int w   = t >> 6;
    const int l   = t & 63;
    const int l31 = l & 31, lhi = l >> 5;
    const int bh  = blockIdx.y, h = bh & 3, b = bh >> 2;
    const int s0  = blockIdx.x * 32;

    const float* xrow = x + ((size_t)(b*S_ + s0 + l31))*D_ + h*DH_;
    v8s af[4];
    #pragma unroll
    for (int k0 = 0; k0 < 4; ++k0)
        af[k0] = cvt8(xrow + k0*16 + lhi*8);

    const float* Wp[3] = { qw + h*DH_*DH_, kw + h*DH_*DH_, vw + h*DH_*DH_ };
    const float* Bp[3] = { qb + h*DH_,     kb + h*DH_,     vb + h*DH_ };
    short* Qh = Qo + (size_t)bh*S_*DH_;
    short* Kh = Ko + (size_t)bh*S_*DH_;

    #pragma unroll
    for (int ui = 0; ui < 3; ++ui) {
        const int u  = w*3 + ui;
        const int p  = u >> 1;
        const int eb = u & 1;
        const int e  = eb*32 + l31;
        const float* wrow = Wp[p] + e*DH_;

        v16f acc = vz16();
        #pragma unroll
        for (int k0 = 0; k0 < 4; ++k0) {
            v8s bfr = cvt8(wrow + k0*16 + lhi*8);
            acc = __builtin_amdgcn_mfma_f32_32x32x16_bf16(af[k0], bfr, acc, 0, 0, 0);
        }

        const float bias = Bp[p][e];
        if (p == 0) {
            const float bq = bias * QSCL;
            #pragma unroll
            for (int r = 0; r < 16; ++r) acc[r] = fmaf(acc[r], QSCL, bq);
        } else {
            #pragma unroll
            for (int r = 0; r < 16; ++r) acc[r] += bias;
        }

        if (p < 2) {
            short* dst = (p == 0) ? Qh : Kh;
            #pragma unroll
            for (int r = 0; r < 16; ++r) {
                int s = s0 + (r & 3) + 8*(r >> 2) + 4*lhi;
                dst[(size_t)s*DH_ + e] = f2bf(acc[r]);
            }
        } else {
            short* vtb = Vt + (size_t)bh*DH_*S_ + (size_t)e*S_;
            #pragma unroll
            for (int rq = 0; rq < 4; ++rq) {
                v2u pr = { cvtpk(acc[rq*4+0], acc[rq*4+1]),
                           cvtpk(acc[rq*4+2], acc[rq*4+3]) };
                int s = s0 + rq*8 + 4*lhi;
                *(v2u*)(vtb + s) = pr;
            }
        }
    }
}

// ---------------------------------------------------------------------------
// Kernel 2: flash attention (R13/R14 loop) + fused split-K combine.
// Fragment layouts (m74/m101):
//   A: row=lane&31, k=(lane>>5)*8+j ; B: col=lane&31, k=(lane>>5)*8+j
//   C/D: col=lane&31, row=(reg&3)+8*(reg>>2)+4*(lane>>5)
// LDS tiles [64 rows][8 chunks of 16B], chunk slot = c ^ (row&7) (T2).
// ---------------------------------------------------------------------------
__global__ __launch_bounds__(512, 4) void attn_kernel(
    const short* __restrict__ Q, const short* __restrict__ K,
    const short* __restrict__ Vt, _Float16* __restrict__ Opart,
    float* __restrict__ Ml, int* __restrict__ ctr,
    float* __restrict__ out, int nspl, int kvlen)
{
    __shared__ __align__(16) short klds[2][64][64];
    __shared__ __align__(16) short vlds[2][64][64];

    const int t    = threadIdx.x;
    const int w    = t >> 6;
    const int l    = t & 63;
    const int l31  = l & 31;
    const int lhi  = l >> 5;
    const int bh   = blockIdx.y;
    const int qtil = blockIdx.x;
    const int spl  = blockIdx.z;
    const int q0   = qtil*QB + w*QW;
    const int kv_beg = spl * kvlen;

    const short* Qh = Q  + (size_t)bh*S_*DH_;
    const short* Kh = K  + (size_t)bh*S_*DH_;
    const short* Vh = Vt + (size_t)bh*DH_*S_;

    // staging: wave w stages rows w*8..w*8+7; source chunk pre-swizzled (T2)
    const int rl  = l >> 3;
    const int cs  = (l & 7) ^ (rl & 7);
    const size_t koff = (size_t)(w*8 + rl)*DH_ + cs*8;
    const size_t voff = (size_t)(w*8 + rl)*S_  + cs*8;
    const int ldst = w*512 + l*8;

    // Q B-frags (per-wave constant)
    v8s qf[4];
    #pragma unroll
    for (int k0 = 0; k0 < 4; ++k0)
        qf[k0] = *(const v8s*)(Qh + (size_t)(q0 + l31)*DH_ + k0*16 + lhi*8);

    // swizzled frag-read offsets
    int fo[2][4];
    #pragma unroll
    for (int a = 0; a < 2; ++a)
        #pragma unroll
        for (int c = 0; c < 4; ++c)
            fo[a][c] = (a*32 + l31)*64 + (((c*2 + lhi) ^ (l31 & 7))*8);

    v16f o0 = vz16(), o1 = vz16();
    float l_run = 0.f;

    const int NT = kvlen / KVB;

    // prologue: stage tile 0 into buf 0
    {
        v8s k0v = *(const v8s*)(Kh + (size_t)kv_beg*DH_ + koff);
        v8s v0v = *(const v8s*)(Vh + kv_beg + voff);
        *(v8s*)((short*)klds[0] + ldst) = k0v;
        *(v8s*)((short*)vlds[0] + ldst) = v0v;
    }
    __syncthreads();

    for (int it = 0; it < NT; ++it) {
        const int cur = it & 1;

        // T14 async-split: issue next tile's global loads before compute
        v8s knx, vnx;
        if (it + 1 < NT) {
            size_t kvn = kv_beg + (size_t)(it+1)*KVB;
            knx = *(const v8s*)(Kh + kvn*DH_ + koff);
            vnx = *(const v8s*)(Vh + kvn + voff);
        }

        const short* kb = (const short*)klds[cur];
        const short* vb = (const short*)vlds[cur];

        // --- QK^T (swapped): S^T[kv][q], 2 kv-halves of 32 ---
        v16f s0 = vz16(), s1 = vz16();
        __builtin_amdgcn_s_setprio(1);
        #pragma unroll
        for (int k0 = 0; k0 < 4; ++k0) {
            v8s a0 = *(const v8s*)(kb + fo[0][k0]);
            v8s a1 = *(const v8s*)(kb + fo[1][k0]);
            s0 = __builtin_amdgcn_mfma_f32_32x32x16_bf16(a0, qf[k0], s0, 0, 0, 0);
            s1 = __builtin_amdgcn_mfma_f32_32x32x16_bf16(a1, qf[k0], s1, 0, 0, 0);
        }
        __builtin_amdgcn_s_setprio(0);

        // --- softmax numerator: p = exp2(s), no max subtraction ---
        #pragma unroll
        for (int i = 0; i < 16; ++i) s0[i] = fexp2(s0[i]);
        #pragma unroll
        for (int i = 0; i < 16; ++i) s1[i] = fexp2(s1[i]);
        float a16[16];
        #pragma unroll
        for (int i = 0; i < 16; ++i) a16[i] = s0[i] + s1[i];
        #pragma unroll
        for (int st = 8; st; st >>= 1)
            #pragma unroll
            for (int i = 0; i < st; ++i) a16[i] += a16[i+st];
        l_run += xadd32(a16[0]);

        // --- pack P -> 4 PV B-frags (T12: cvt_pk + permlane32_swap) ---
        unsigned pwv[4][4];
        {
            unsigned j0 = cvtpk(s0[0], s0[1]),  j1 = cvtpk(s0[2], s0[3]);
            unsigned j2 = cvtpk(s0[4], s0[5]),  j3 = cvtpk(s0[6], s0[7]);
            unsigned j4 = cvtpk(s0[8], s0[9]),  j5 = cvtpk(s0[10], s0[11]);
            unsigned j6 = cvtpk(s0[12], s0[13]), j7 = cvtpk(s0[14], s0[15]);
            pl32swap(j0, j2); pl32swap(j1, j3);
            pwv[0][0] = j0; pwv[0][1] = j1; pwv[0][2] = j2; pwv[0][3] = j3;
            pl32swap(j4, j6); pl32swap(j5, j7);
            pwv[1][0] = j4; pwv[1][1] = j5; pwv[1][2] = j6; pwv[1][3] = j7;
        }
        {
            unsigned j0 = cvtpk(s1[0], s1[1]),  j1 = cvtpk(s1[2], s1[3]);
            unsigned j2 = cvtpk(s1[4], s1[5]),  j3 = cvtpk(s1[6], s1[7]);
            unsigned j4 = cvtpk(s1[8], s1[9]),  j5 = cvtpk(s1[10], s1[11]);
            unsigned j6 = cvtpk(s1[12], s1[13]), j7 = cvtpk(s1[14], s1[15]);
            pl32swap(j0, j2); pl32swap(j1, j3);
            pwv[2][0] = j0; pwv[2][1] = j1; pwv[2][2] = j2; pwv[2][3] = j3;
            pl32swap(j4, j6); pl32swap(j5, j7);
            pwv[3][0] = j4; pwv[3][1] = j5; pwv[3][2] = j6; pwv[3][3] = j7;
        }

        // --- PV: O^T[d][q] += V^T[d][kv] * P^T[kv][q] ---
        __builtin_amdgcn_s_setprio(1);
        #pragma unroll
        for (int kk = 0; kk < 4; ++kk) {
            v4u u = { pwv[kk][0], pwv[kk][1], pwv[kk][2], pwv[kk][3] };
            v8s pf = __builtin_bit_cast(v8s, u);
            v8s va0 = *(const v8s*)(vb + fo[0][kk]);
            v8s va1 = *(const v8s*)(vb + fo[1][kk]);
            o0 = __builtin_amdgcn_mfma_f32_32x32x16_bf16(va0, pf, o0, 0, 0, 0);
            o1 = __builtin_amdgcn_mfma_f32_32x32x16_bf16(va1, pf, o1, 0, 0, 0);
        }
        __builtin_amdgcn_s_setprio(0);

        // stage next tile into other buffer (loads had whole body to land)
        if (it + 1 < NT) {
            *(v8s*)((short*)klds[cur^1] + ldst) = knx;
            *(v8s*)((short*)vlds[cur^1] + ldst) = vnx;
        }
        __syncthreads();
    }

    // --- epilogue: dump fp16 partial + l, then last-wave fused combine ---
    const int inst = bh*(S_/QW) + qtil*NW + w;
    {
        _Float16* od = Opart + ((size_t)inst*nspl + spl)*2048;
        #pragma unroll
        for (int r = 0; r < 16; ++r) od[r*64 + l]      = (_Float16)o0[r];
        #pragma unroll
        for (int r = 0; r < 16; ++r) od[(16+r)*64 + l] = (_Float16)o1[r];
        Ml[((size_t)inst*nspl + spl)*64 + l] = (l < 32) ? 0.f : l_run;
    }

    __threadfence();                     // release: partials visible device-wide
    int old = 0;
    if (l == 0) old = atomicAdd(&ctr[inst], 1);
    old = __shfl(old, 0);

    if (old == nspl - 1) {               // last split for this instance
        __threadfence();                 // acquire: others' partials visible

        const float* mlp = Ml + (size_t)inst*nspl*64;
        float L = 0.f;
        for (int sp = 0; sp < nspl; ++sp)
            L += mlp[sp*64 + 32 + l31];
        float inv = 1.f / L;

        const _Float16* op0 = Opart + (size_t)inst*nspl*2048;
        const int bh_ = inst >> 7;
        const int qw_ = inst & 127;
        float* outp = out + ((size_t)((bh_ >> 2)*S_ + qw_*32 + l31))*D_
                          + (bh_ & 3)*DH_;

        #pragma unroll
        for (int g = 0; g < 8; ++g) {
            v4f acc;
            #pragma unroll
            for (int jj = 0; jj < 4; ++jj) {
                int r = g*4 + jj;
                float v = 0.f;
                for (int sp = 0; sp < nspl; ++sp)
                    v += (float)op0[sp*2048 + r*64 + l];
                acc[jj] = v * inv;
            }
            int d = (g >> 2)*32 + (g & 3)*8 + lhi*4;
            *(v4f*)(outp + d) = acc;
        }
    }
}

extern "C" void kernel_launch(void* const* d_in, const int* in_sizes, int n_in,
                              void* d_out, int out_size, void* d_ws, size_t ws_size,
                              hipStream_t stream)
{
    const float* x  = (const float*)d_in[0];
    const float* qw = (const float*)d_in[1];
    const float* qb = (const float*)d_in[2];
    const float* kw = (const float*)d_in[3];
    const float* kb = (const float*)d_in[4];
    const float* vw = (const float*)d_in[5];
    const float* vb = (const float*)d_in[6];

    short* Qb  = (short*)d_ws;
    short* Kb  = Qb + NTOK;
    short* Vtb = Kb + NTOK;
    _Float16* Opart = (_Float16*)(Vtb + NTOK);

    size_t base = (size_t)3*NTOK*sizeof(short);
    size_t per_spl = (size_t)NINST*2048*2 + (size_t)NINST*64*4;  // fp16 O + fp32 ml
    size_t ctr_bytes = (size_t)NINST*4;
    int nspl = 1;
    if      (ws_size >= base + 4*per_spl + ctr_bytes) nspl = 4;
    else if (ws_size >= base + 2*per_spl + ctr_bytes) nspl = 2;
    float* Ml = (float*)(Opart + (size_t)NINST*nspl*2048);
    int* ctr = (int*)(Ml + (size_t)NINST*nspl*64);
    int kvlen = S_/nspl;

    float* out = (float*)d_out;

    // zero the per-instance arrival counters (graph-capturable async memset)
    hipMemsetAsync(ctr, 0, ctr_bytes, stream);

    dim3 pg(S_/32, BH_), pb(128);
    hipLaunchKernelGGL(qkv_proj_mfma, pg, pb, 0, stream,
                       x, qw, qb, kw, kb, vw, vb, Qb, Kb, Vtb);

    dim3 ag(S_/QB, BH_, nspl), ab(512);
    hipLaunchKernelGGL(attn_kernel, ag, ab, 0, stream, Qb, Kb, Vtb,
                       Opart, Ml, ctr, out, nspl, kvlen);
}

// Round 17
// 60.543 us; speedup vs baseline: 3.5221x; 3.5221x over previous
//
#include <hip/hip_runtime.h>
#include <hip/hip_bf16.h>
#include <hip/hip_fp16.h>

// MSA: B=2, S=4096, D=256, H=4, DH=64. fp32 in/out, bf16 MFMA internally.
// R17: R16 retry (compile fix: cvt_pkrtz via inline asm -- the builtin
//      returns __fp16x2 which mismatches _Float16x2). Packed u32 partials:
//      attn epilogue packs 2xfp16 per dword, combine reads dwords --
//      halves epilogue stores and combine loads (G13). Attn loop body
//      unchanged (R13/R14 floor, regs <=124 hard rule).

#define B_   2
#define S_   4096
#define D_   256
#define H_   4
#define DH_  64
#define BH_  8
#define NTOK (BH_*S_*DH_)   // elements per Q/K/V buffer

#define KVB  64             // kv tile per step
#define QW   32             // q rows per wave
#define NW   8              // waves per block
#define QB   (QW*NW)        // 256 q rows per block
#define NINST (BH_*(S_/QW)) // 1024 q-wave instances

typedef short v8s __attribute__((ext_vector_type(8)));
typedef float v16f __attribute__((ext_vector_type(16)));
typedef float v4f __attribute__((ext_vector_type(4)));
typedef unsigned v4u __attribute__((ext_vector_type(4)));
typedef unsigned v2u __attribute__((ext_vector_type(2)));
typedef int v2i __attribute__((ext_vector_type(2)));
typedef _Float16 h2 __attribute__((ext_vector_type(2)));

#define QSCL (0.125f * 1.4426950408889634f)   // 1/sqrt(64) * log2(e)

static __device__ __forceinline__ short f2bf(float f) {
    __hip_bfloat16 h = __float2bfloat16(f);
    return *reinterpret_cast<short*>(&h);
}
static __device__ __forceinline__ unsigned cvtpk(float lo, float hi) {
    unsigned r;
    asm("v_cvt_pk_bf16_f32 %0, %1, %2" : "=v"(r) : "v"(lo), "v"(hi));
    return r;
}
// pack 2 fp32 -> 2 fp16 in one dword (RTZ; err ~1e-3 ok vs 5e-3 threshold)
static __device__ __forceinline__ unsigned pkf16(float lo, float hi) {
    unsigned r;
    asm("v_cvt_pkrtz_f16_f32 %0, %1, %2" : "=v"(r) : "v"(lo), "v"(hi));
    return r;
}
// Raw v_exp_f32: args bounded (|s|<~3 in exp2 domain), no wrapper needed.
static __device__ __forceinline__ float fexp2(float x) {
#if __has_builtin(__builtin_amdgcn_exp2f)
    return __builtin_amdgcn_exp2f(x);
#else
    float r;
    asm("v_exp_f32 %0, %1" : "=v"(r) : "v"(x));
    return r;
#endif
}
static __device__ __forceinline__ void pl32swap(unsigned &a, unsigned &b) {
#if __has_builtin(__builtin_amdgcn_permlane32_swap)
    v2i r = __builtin_amdgcn_permlane32_swap((int)a, (int)b, false, false);
    a = (unsigned)r[0]; b = (unsigned)r[1];
#else
    asm volatile("v_permlane32_swap_b32 %0, %1" : "+v"(a), "+v"(b));
#endif
}
// cross-half (lane i <-> i+32) add via permlane self-swap
static __device__ __forceinline__ float xadd32(float x) {
    unsigned a = __builtin_bit_cast(unsigned, x), b = a;
    pl32swap(a, b);
    return __builtin_bit_cast(float, a) + __builtin_bit_cast(float, b);
}
static __device__ __forceinline__ v16f vz16() {
    v16f z;
    #pragma unroll
    for (int i = 0; i < 16; ++i) z[i] = 0.f;
    return z;
}
static __device__ __forceinline__ v8s cvt8(const float* p) {
    v4f f0 = *(const v4f*)(p);
    v4f f1 = *(const v4f*)(p + 4);
    v4u u = { cvtpk(f0[0], f0[1]), cvtpk(f0[2], f0[3]),
              cvtpk(f1[0], f1[1]), cvtpk(f1[2], f1[3]) };
    return __builtin_bit_cast(v8s, u);
}

// ---------------------------------------------------------------------------
// Kernel 1: MFMA QKV projection (R5, unchanged).
//   Q: [BH][S][DH] pre-scaled by QSCL; K: [BH][S][DH]; Vt: [BH][DH][S].
// ---------------------------------------------------------------------------
__global__ __launch_bounds__(128) void qkv_proj_mfma(
    const float* __restrict__ x,
    const float* __restrict__ qw, const float* __restrict__ qb,
    const float* __restrict__ kw, const float* __restrict__ kb,
    const float* __restrict__ vw, const float* __restrict__ vb,
    short* __restrict__ Qo, short* __restrict__ Ko, short* __restrict__ Vt)
{
    const int t   = threadIdx.x;
    const int w   = t >> 6;
    const int l   = t & 63;
    const int l31 = l & 31, lhi = l >> 5;
    const int bh  = blockIdx.y, h = bh & 3, b = bh >> 2;
    const int s0  = blockIdx.x * 32;

    const float* xrow = x + ((size_t)(b*S_ + s0 + l31))*D_ + h*DH_;
    v8s af[4];
    #pragma unroll
    for (int k0 = 0; k0 < 4; ++k0)
        af[k0] = cvt8(xrow + k0*16 + lhi*8);

    const float* Wp[3] = { qw + h*DH_*DH_, kw + h*DH_*DH_, vw + h*DH_*DH_ };
    const float* Bp[3] = { qb + h*DH_,     kb + h*DH_,     vb + h*DH_ };
    short* Qh = Qo + (size_t)bh*S_*DH_;
    short* Kh = Ko + (size_t)bh*S_*DH_;

    #pragma unroll
    for (int ui = 0; ui < 3; ++ui) {
        const int u  = w*3 + ui;
        const int p  = u >> 1;
        const int eb = u & 1;
        const int e  = eb*32 + l31;
        const float* wrow = Wp[p] + e*DH_;

        v16f acc = vz16();
        #pragma unroll
        for (int k0 = 0; k0 < 4; ++k0) {
            v8s bfr = cvt8(wrow + k0*16 + lhi*8);
            acc = __builtin_amdgcn_mfma_f32_32x32x16_bf16(af[k0], bfr, acc, 0, 0, 0);
        }

        const float bias = Bp[p][e];
        if (p == 0) {
            const float bq = bias * QSCL;
            #pragma unroll
            for (int r = 0; r < 16; ++r) acc[r] = fmaf(acc[r], QSCL, bq);
        } else {
            #pragma unroll
            for (int r = 0; r < 16; ++r) acc[r] += bias;
        }

        if (p < 2) {
            short* dst = (p == 0) ? Qh : Kh;
            #pragma unroll
            for (int r = 0; r < 16; ++r) {
                int s = s0 + (r & 3) + 8*(r >> 2) + 4*lhi;
                dst[(size_t)s*DH_ + e] = f2bf(acc[r]);
            }
        } else {
            short* vtb = Vt + (size_t)bh*DH_*S_ + (size_t)e*S_;
            #pragma unroll
            for (int rq = 0; rq < 4; ++rq) {
                v2u pr = { cvtpk(acc[rq*4+0], acc[rq*4+1]),
                           cvtpk(acc[rq*4+2], acc[rq*4+3]) };
                int s = s0 + rq*8 + 4*lhi;
                *(v2u*)(vtb + s) = pr;
            }
        }
    }
}

// ---------------------------------------------------------------------------
// Kernel 2: flash attention (R13/R14 loop, unchanged), swapped QK^T,
// 32x32x16 MFMA, no online max (scores bounded in exp2 domain).
// Fragment layouts (m74/m101):
//   A: row=lane&31, k=(lane>>5)*8+j ; B: col=lane&31, k=(lane>>5)*8+j
//   C/D: col=lane&31, row=(reg&3)+8*(reg>>2)+4*(lane>>5)
// LDS tiles [64 rows][8 chunks of 16B], chunk slot = c ^ (row&7) (T2).
// Epilogue: partials packed 2xfp16/dword, layout u32[16][64] per split.
// ---------------------------------------------------------------------------
__global__ __launch_bounds__(512, 4) void attn_kernel(
    const short* __restrict__ Q, const short* __restrict__ K,
    const short* __restrict__ Vt, unsigned* __restrict__ Opart,
    float* __restrict__ Ml, int nspl, int kvlen)
{
    __shared__ __align__(16) short klds[2][64][64];
    __shared__ __align__(16) short vlds[2][64][64];

    const int t    = threadIdx.x;
    const int w    = t >> 6;
    const int l    = t & 63;
    const int l31  = l & 31;
    const int lhi  = l >> 5;
    const int bh   = blockIdx.y;
    const int qtil = blockIdx.x;
    const int spl  = blockIdx.z;
    const int q0   = qtil*QB + w*QW;
    const int kv_beg = spl * kvlen;

    const short* Qh = Q  + (size_t)bh*S_*DH_;
    const short* Kh = K  + (size_t)bh*S_*DH_;
    const short* Vh = Vt + (size_t)bh*DH_*S_;

    // staging: wave w stages rows w*8..w*8+7; source chunk pre-swizzled (T2)
    const int rl  = l >> 3;
    const int cs  = (l & 7) ^ (rl & 7);
    const size_t koff = (size_t)(w*8 + rl)*DH_ + cs*8;
    const size_t voff = (size_t)(w*8 + rl)*S_  + cs*8;
    const int ldst = w*512 + l*8;

    // Q B-frags (per-wave constant)
    v8s qf[4];
    #pragma unroll
    for (int k0 = 0; k0 < 4; ++k0)
        qf[k0] = *(const v8s*)(Qh + (size_t)(q0 + l31)*DH_ + k0*16 + lhi*8);

    // swizzled frag-read offsets
    int fo[2][4];
    #pragma unroll
    for (int a = 0; a < 2; ++a)
        #pragma unroll
        for (int c = 0; c < 4; ++c)
            fo[a][c] = (a*32 + l31)*64 + (((c*2 + lhi) ^ (l31 & 7))*8);

    v16f o0 = vz16(), o1 = vz16();
    float l_run = 0.f;

    const int NT = kvlen / KVB;

    // prologue: stage tile 0 into buf 0
    {
        v8s k0v = *(const v8s*)(Kh + (size_t)kv_beg*DH_ + koff);
        v8s v0v = *(const v8s*)(Vh + kv_beg + voff);
        *(v8s*)((short*)klds[0] + ldst) = k0v;
        *(v8s*)((short*)vlds[0] + ldst) = v0v;
    }
    __syncthreads();

    for (int it = 0; it < NT; ++it) {
        const int cur = it & 1;

        // T14 async-split: issue next tile's global loads before compute
        v8s knx, vnx;
        if (it + 1 < NT) {
            size_t kvn = kv_beg + (size_t)(it+1)*KVB;
            knx = *(const v8s*)(Kh + kvn*DH_ + koff);
            vnx = *(const v8s*)(Vh + kvn + voff);
        }

        const short* kb = (const short*)klds[cur];
        const short* vb = (const short*)vlds[cur];

        // --- QK^T (swapped): S^T[kv][q], 2 kv-halves of 32 ---
        v16f s0 = vz16(), s1 = vz16();
        __builtin_amdgcn_s_setprio(1);
        #pragma unroll
        for (int k0 = 0; k0 < 4; ++k0) {
            v8s a0 = *(const v8s*)(kb + fo[0][k0]);
            v8s a1 = *(const v8s*)(kb + fo[1][k0]);
            s0 = __builtin_amdgcn_mfma_f32_32x32x16_bf16(a0, qf[k0], s0, 0, 0, 0);
            s1 = __builtin_amdgcn_mfma_f32_32x32x16_bf16(a1, qf[k0], s1, 0, 0, 0);
        }
        __builtin_amdgcn_s_setprio(0);

        // --- softmax numerator: p = exp2(s), no max subtraction ---
        #pragma unroll
        for (int i = 0; i < 16; ++i) s0[i] = fexp2(s0[i]);
        #pragma unroll
        for (int i = 0; i < 16; ++i) s1[i] = fexp2(s1[i]);
        float a16[16];
        #pragma unroll
        for (int i = 0; i < 16; ++i) a16[i] = s0[i] + s1[i];
        #pragma unroll
        for (int st = 8; st; st >>= 1)
            #pragma unroll
            for (int i = 0; i < st; ++i) a16[i] += a16[i+st];
        l_run += xadd32(a16[0]);

        // --- pack P -> 4 PV B-frags (T12: cvt_pk + permlane32_swap) ---
        unsigned pwv[4][4];
        {
            unsigned j0 = cvtpk(s0[0], s0[1]),  j1 = cvtpk(s0[2], s0[3]);
            unsigned j2 = cvtpk(s0[4], s0[5]),  j3 = cvtpk(s0[6], s0[7]);
            unsigned j4 = cvtpk(s0[8], s0[9]),  j5 = cvtpk(s0[10], s0[11]);
            unsigned j6 = cvtpk(s0[12], s0[13]), j7 = cvtpk(s0[14], s0[15]);
            pl32swap(j0, j2); pl32swap(j1, j3);
            pwv[0][0] = j0; pwv[0][1] = j1; pwv[0][2] = j2; pwv[0][3] = j3;
            pl32swap(j4, j6); pl32swap(j5, j7);
            pwv[1][0] = j4; pwv[1][1] = j5; pwv[1][2] = j6; pwv[1][3] = j7;
        }
        {
            unsigned j0 = cvtpk(s1[0], s1[1]),  j1 = cvtpk(s1[2], s1[3]);
            unsigned j2 = cvtpk(s1[4], s1[5]),  j3 = cvtpk(s1[6], s1[7]);
            unsigned j4 = cvtpk(s1[8], s1[9]),  j5 = cvtpk(s1[10], s1[11]);
            unsigned j6 = cvtpk(s1[12], s1[13]), j7 = cvtpk(s1[14], s1[15]);
            pl32swap(j0, j2); pl32swap(j1, j3);
            pwv[2][0] = j0; pwv[2][1] = j1; pwv[2][2] = j2; pwv[2][3] = j3;
            pl32swap(j4, j6); pl32swap(j5, j7);
            pwv[3][0] = j4; pwv[3][1] = j5; pwv[3][2] = j6; pwv[3][3] = j7;
        }

        // --- PV: O^T[d][q] += V^T[d][kv] * P^T[kv][q] ---
        __builtin_amdgcn_s_setprio(1);
        #pragma unroll
        for (int kk = 0; kk < 4; ++kk) {
            v4u u = { pwv[kk][0], pwv[kk][1], pwv[kk][2], pwv[kk][3] };
            v8s pf = __builtin_bit_cast(v8s, u);
            v8s va0 = *(const v8s*)(vb + fo[0][kk]);
            v8s va1 = *(const v8s*)(vb + fo[1][kk]);
            o0 = __builtin_amdgcn_mfma_f32_32x32x16_bf16(va0, pf, o0, 0, 0, 0);
            o1 = __builtin_amdgcn_mfma_f32_32x32x16_bf16(va1, pf, o1, 0, 0, 0);
        }
        __builtin_amdgcn_s_setprio(0);

        // stage next tile into other buffer (loads had whole body to land)
        if (it + 1 < NT) {
            *(v8s*)((short*)klds[cur^1] + ldst) = knx;
            *(v8s*)((short*)vlds[cur^1] + ldst) = vnx;
        }
        __syncthreads();
    }

    // --- epilogue: packed fp16x2 partials (u32[16][64] per split) + l ---
    const int inst = bh*(S_/QW) + qtil*NW + w;
    unsigned* od = Opart + ((size_t)inst*nspl + spl)*1024;
    #pragma unroll
    for (int r2 = 0; r2 < 8; ++r2)
        od[r2*64 + l] = pkf16(o0[2*r2], o0[2*r2+1]);
    #pragma unroll
    for (int r2 = 0; r2 < 8; ++r2)
        od[(8+r2)*64 + l] = pkf16(o1[2*r2], o1[2*r2+1]);
    Ml[((size_t)inst*nspl + spl)*64 + l] = (l < 32) ? 0.f : l_run;
}

// ---------------------------------------------------------------------------
// Kernel 3: merge packed fp16x2 partials, normalize, write fp32 out.
// u32 row r2 holds O rows (2*r2, 2*r2+1); acc rows r=g*4+jj map to
// u32 rows g*2, g*2+1 (pairs within the v4f store).
// ---------------------------------------------------------------------------
template<int NSPL>
__global__ __launch_bounds__(256) void combine_kernel(
    const unsigned* __restrict__ Opart, const float* __restrict__ Ml,
    float* __restrict__ out)
{
    const int t = threadIdx.x;
    const int w = t >> 6, l = t & 63;
    const int inst = blockIdx.x*4 + w;
    const int bh = inst >> 7;
    const int qw = inst & 127;
    const int b = bh >> 2, h = bh & 3;
    const int l31 = l & 31, lhi = l >> 5;
    const int q = qw*32 + l31;

    const float* mlp = Ml + (size_t)inst*NSPL*64;
    float L = 0.f;
    #pragma unroll
    for (int sp = 0; sp < NSPL; ++sp)
        L += mlp[sp*64 + 32 + l31];
    float inv = 1.f / L;

    const unsigned* op0 = Opart + (size_t)inst*NSPL*1024;
    float* outp = out + ((size_t)(b*S_ + q))*D_ + h*DH_;

    #pragma unroll
    for (int g = 0; g < 8; ++g) {
        float a0 = 0.f, a1 = 0.f, a2 = 0.f, a3 = 0.f;
        #pragma unroll
        for (int sp = 0; sp < NSPL; ++sp) {
            h2 pa = __builtin_bit_cast(h2, op0[sp*1024 + (g*2)*64 + l]);
            h2 pb = __builtin_bit_cast(h2, op0[sp*1024 + (g*2+1)*64 + l]);
            a0 += (float)pa[0]; a1 += (float)pa[1];
            a2 += (float)pb[0]; a3 += (float)pb[1];
        }
        v4f acc = { a0*inv, a1*inv, a2*inv, a3*inv };
        int d = (g >> 2)*32 + (g & 3)*8 + lhi*4;
        *(v4f*)(outp + d) = acc;
    }
}

extern "C" void kernel_launch(void* const* d_in, const int* in_sizes, int n_in,
                              void* d_out, int out_size, void* d_ws, size_t ws_size,
                              hipStream_t stream)
{
    const float* x  = (const float*)d_in[0];
    const float* qw = (const float*)d_in[1];
    const float* qb = (const float*)d_in[2];
    const float* kw = (const float*)d_in[3];
    const float* kb = (const float*)d_in[4];
    const float* vw = (const float*)d_in[5];
    const float* vb = (const float*)d_in[6];

    short* Qb  = (short*)d_ws;
    short* Kb  = Qb + NTOK;
    short* Vtb = Kb + NTOK;
    unsigned* Opart = (unsigned*)(Vtb + NTOK);

    size_t base = (size_t)3*NTOK*sizeof(short);
    size_t per_spl = (size_t)NINST*1024*4 + (size_t)NINST*64*4;  // u32 O + fp32 ml
    int nspl = 1;
    if      (ws_size >= base + 4*per_spl) nspl = 4;
    else if (ws_size >= base + 2*per_spl) nspl = 2;
    float* Ml = (float*)(Opart + (size_t)NINST*nspl*1024);
    int kvlen = S_/nspl;

    float* out = (float*)d_out;

    dim3 pg(S_/32, BH_), pb(128);
    hipLaunchKernelGGL(qkv_proj_mfma, pg, pb, 0, stream,
                       x, qw, qb, kw, kb, vw, vb, Qb, Kb, Vtb);

    dim3 ag(S_/QB, BH_, nspl), ab(512);
    hipLaunchKernelGGL(attn_kernel, ag, ab, 0, stream, Qb, Kb, Vtb,
                       Opart, Ml, nspl, kvlen);

    dim3 cg(NINST/4), cb(256);
    if (nspl == 4)
        hipLaunchKernelGGL(combine_kernel<4>, cg, cb, 0, stream, Opart, Ml, out);
    else if (nspl == 2)
        hipLaunchKernelGGL(combine_kernel<2>, cg, cb, 0, stream, Opart, Ml, out);
    else
        hipLaunchKernelGGL(combine_kernel<1>, cg, cb, 0, stream, Opart, Ml, out);
}